// Round 1
// 513.305 us; speedup vs baseline: 1.2344x; 1.2344x over previous
//
#include <hip/hip_runtime.h>
#include <math.h>
#include <stddef.h>

// ---------------- problem constants ----------------
constexpr int T_ = 64;
constexpr int H_ = 1024;
constexpr int W_ = 1024;
constexpr int N_ = H_ * W_;
// int((1.0-0.15)*(N-1)) and int(0.3*(N-1)) with python double semantics
constexpr unsigned RANK_G = 891288;   // 85th pct index of gm (ascending, 0-based)
constexpr unsigned RANK_B = 314572;   // 30th pct index of |f|

constexpr int ROWS_PER_BLOCK = 32;
constexpr int BLOCKS_PER_FRAME = H_ / ROWS_PER_BLOCK; // 32

// sampling: 16 rows/frame = 16384 samples; N/NS = 64
constexpr int SROWS = 16;
constexpr int NS = SROWS * W_;              // 16384
constexpr int SHB = 8192;                   // stage-1 buckets (u>>18)
constexpr int MARGIN = 192;                 // sample-rank margin (~4.4 sigma in pop rank)
constexpr int RS_G = (int)(RANK_G / 64);    // 13926
constexpr int RS_B = (int)(RANK_B / 64);    // 4915

// per-block segment capacities (expected ~770 / ~770 / ~125)
constexpr unsigned CAPG = 1536;
constexpr unsigned CAPB = 1536;
constexpr unsigned CAPX = 448;

// select kernel LDS cache of candidate deltas (104 KB); expected total ~24.6K
constexpr unsigned CACHE_N = 26624;
constexpr int SEL_THREADS = 512;

// resolve parallelism: 8 blocks per frame, 4 segments each
constexpr int RES_SPLIT = 8;

// ---------------- workspace layout (~49 MB) ----------------
struct WS {
  unsigned lo[2][T_], hi[2][T_];       // refined value brackets (bit patterns)
  unsigned cntG[T_][32], cntB[T_][32], cntX[T_][32];
  unsigned cbG[T_][32], cbB[T_][32];   // per-block #{u < lo}
  float    thr[2][T_];
  double   part[T_][32][4];            // per-block certain-true partial stats
  double   acc2[T_][RES_SPLIT][4];     // resolve partials: cnt, sum_gm, sum_gm*x, sum_gm*y
  unsigned Gg[T_][32][CAPG];           // gm bracket candidates: gm bits
  unsigned Ga[T_][32][CAPG];           //   aux: x|y<<10|certain_bz_flag<<20
  unsigned Bb[T_][32][CAPB];           // bz bracket candidates: bz bits
  unsigned Xg[T_][32][CAPX];           // uncertain-stats records (bz in bracket, gm >= lo_g)
  unsigned Xb[T_][32][CAPX];
  unsigned Xa[T_][32][CAPX];           //   aux: x|y<<10
};

// Shared gm computation so every pass rounds identically.
__device__ __forceinline__ float gm_at(float cur, float right, float down,
                                       int col, int row) {
  float gx = (col < W_ - 1) ? (right - cur) : 0.0f;
  float gy = (row < H_ - 1) ? (down - cur) : 0.0f;
  return sqrtf(gx * gx + gy * gy);
}

// ---------------- pass 0: sampled bracket estimation (2-stage refine) ----------
__global__ __launch_bounds__(256) void sample_kernel(const float* __restrict__ frames,
                                                     WS* ws) {
  const int t = blockIdx.x;
  __shared__ unsigned hist[2][SHB];        // 64 KB
  __shared__ unsigned sub[4][1024];        // 16 KB, (q*2+e)
  __shared__ unsigned partial[256], chunk_before[256];
  __shared__ unsigned selB[4], selCB[4];
  const int tx = threadIdx.x, c = tx * 4;
  for (int i = tx; i < 2 * SHB; i += 256) (&hist[0][0])[i] = 0;
  for (int i = tx; i < 4 * 1024; i += 256) (&sub[0][0])[i] = 0;
  __syncthreads();
  const float* f = frames + (size_t)t * N_;

  // stage-1 histogram over 16 sampled rows
  for (int r = 0; r < SROWS; ++r) {
    const int h = r * 64 + 32;                 // 32..992, h+1 always valid
    const float* row = f + (size_t)h * W_;
    float4 a = *(const float4*)(row + c);
    float an = (c + 4 < W_) ? row[c + 4] : 0.0f;
    float4 b = *(const float4*)(row + W_ + c);
    float xs[5] = {a.x, a.y, a.z, a.w, an};
    float ys[4] = {b.x, b.y, b.z, b.w};
#pragma unroll
    for (int j = 0; j < 4; ++j) {
      float gm = gm_at(xs[j], xs[j + 1], ys[j], c + j, h);
      float bz = fabsf(xs[j]);
      atomicAdd(&hist[0][__float_as_uint(gm) >> 18], 1u);
      atomicAdd(&hist[1][__float_as_uint(bz) >> 18], 1u);
    }
  }
  __syncthreads();

  // stage-1 select: bucket + count-below-bucket for each (q, endpoint)
  for (int q = 0; q < 2; ++q) {
    unsigned s = 0;
    for (int j = 0; j < SHB / 256; ++j) s += hist[q][tx * (SHB / 256) + j];
    partial[tx] = s;
    __syncthreads();
    if (tx == 0) {
      unsigned cum = 0;
      for (int i = 0; i < 256; ++i) { chunk_before[i] = cum; cum += partial[i]; }
    }
    __syncthreads();
    for (int e = 0; e < 2; ++e) {
      int k = (q == 0 ? RS_G : RS_B) + (e == 0 ? -MARGIN : MARGIN);
      unsigned cb = chunk_before[tx];
      if ((unsigned)k >= cb && (unsigned)k < cb + partial[tx]) {
        unsigned rem = (unsigned)k - cb, cum = 0;
        for (int j = 0; j < SHB / 256; ++j) {
          unsigned hv = hist[q][tx * (SHB / 256) + j];
          if (rem < cum + hv) {
            selB[q * 2 + e]  = tx * (SHB / 256) + j;
            selCB[q * 2 + e] = cb + cum;
            break;
          }
          cum += hv;
        }
      }
    }
    __syncthreads();
  }

  // stage-2 histogram: re-read samples, refine within selected buckets
  for (int r = 0; r < SROWS; ++r) {
    const int h = r * 64 + 32;
    const float* row = f + (size_t)h * W_;
    float4 a = *(const float4*)(row + c);
    float an = (c + 4 < W_) ? row[c + 4] : 0.0f;
    float4 b = *(const float4*)(row + W_ + c);
    float xs[5] = {a.x, a.y, a.z, a.w, an};
    float ys[4] = {b.x, b.y, b.z, b.w};
#pragma unroll
    for (int j = 0; j < 4; ++j) {
      float gm = gm_at(xs[j], xs[j + 1], ys[j], c + j, h);
      float bz = fabsf(xs[j]);
      unsigned ug = __float_as_uint(gm), ub = __float_as_uint(bz);
#pragma unroll
      for (int e = 0; e < 2; ++e) {
        if ((ug >> 18) == selB[e])     atomicAdd(&sub[e][(ug >> 8) & 1023u], 1u);
        if ((ub >> 18) == selB[2 + e]) atomicAdd(&sub[2 + e][(ub >> 8) & 1023u], 1u);
      }
    }
  }
  __syncthreads();

  // stage-2 select per (q,e) -> refined bound at 2^8 bit granularity
  for (int qe = 0; qe < 4; ++qe) {
    unsigned s = 0;
    for (int j = 0; j < 4; ++j) s += sub[qe][tx * 4 + j];
    partial[tx] = s;
    __syncthreads();
    if (tx == 0) {
      unsigned cum = 0;
      for (int i = 0; i < 256; ++i) { chunk_before[i] = cum; cum += partial[i]; }
    }
    __syncthreads();
    int q = qe >> 1, e = qe & 1;
    int k0 = (q == 0 ? RS_G : RS_B) + (e == 0 ? -MARGIN : MARGIN);
    unsigned k = (unsigned)k0 - selCB[qe];      // rank within bucket
    unsigned cb = chunk_before[tx];
    if (k >= cb && k < cb + partial[tx]) {
      unsigned rem = k - cb, cum = 0;
      for (int j = 0; j < 4; ++j) {
        unsigned hv = sub[qe][tx * 4 + j];
        if (rem < cum + hv) {
          unsigned sb = tx * 4 + j;
          unsigned bound = (selB[qe] << 18) | (sb << 8);
          if (e == 0) ws->lo[q][t] = bound;
          else        ws->hi[q][t] = bound + 256u;
          break;
        }
        cum += hv;
      }
    }
    __syncthreads();
  }
}

// ---------------- pass 1: the ONLY full streaming pass ----------------
__global__ __launch_bounds__(256) void main_kernel(const float* __restrict__ frames,
                                                   WS* ws) {
  const int t = blockIdx.y, blk = blockIdx.x, r0 = blk * ROWS_PER_BLOCK;
  const unsigned lg = ws->lo[0][t], hg = ws->hi[0][t];
  const unsigned lb = ws->lo[1][t], hb = ws->hi[1][t];
  __shared__ unsigned cnt[3];
  const int tx = threadIdx.x, c = tx * 4, lane = tx & 63, wave = tx >> 6;
  if (tx < 3) cnt[tx] = 0;
  __syncthreads();
  unsigned* __restrict__ Gg = ws->Gg[t][blk];
  unsigned* __restrict__ Ga = ws->Ga[t][blk];
  unsigned* __restrict__ Bb = ws->Bb[t][blk];
  unsigned* __restrict__ Xg = ws->Xg[t][blk];
  unsigned* __restrict__ Xb = ws->Xb[t][blk];
  unsigned* __restrict__ Xa = ws->Xa[t][blk];
  const float* f = frames + (size_t)t * N_;

  unsigned cbg = 0, cbb = 0;
  float s0 = 0.f, s1 = 0.f, s2 = 0.f, s3 = 0.f;

  // register-carry the row: row h+1 is loaded once as `b`, reused as `a` next iter
  const float* row0 = f + (size_t)r0 * W_;
  float4 a = *(const float4*)(row0 + c);
  float an = (c + 4 < W_) ? row0[c + 4] : 0.0f;

  for (int r = 0; r < ROWS_PER_BLOCK; ++r) {
    const int h = r0 + r;
    float4 b; float bn;
    if (h + 1 < H_) {
      const float* rowN = f + (size_t)(h + 1) * W_;
      b  = *(const float4*)(rowN + c);
      bn = (c + 4 < W_) ? rowN[c + 4] : 0.0f;
    } else {
      b = a; bn = an;                         // forces gy = 0
    }
    float xs[5] = {a.x, a.y, a.z, a.w, an};
    float ys[4] = {b.x, b.y, b.z, b.w};
#pragma unroll
    for (int j = 0; j < 4; ++j) {
      float gm = gm_at(xs[j], xs[j + 1], ys[j], c + j, h);
      float bz = fabsf(xs[j]);
      unsigned ug = __float_as_uint(gm);
      unsigned ub = __float_as_uint(bz);
      bool bz_lo = (ub < lb);
      if (ug < lg) {
        cbg++;
      } else if (ug < hg) {                    // gm bracket candidate
        unsigned o = atomicAdd(&cnt[0], 1u);
        if (o < CAPG) {
          Gg[o] = ug;
          Ga[o] = (unsigned)(c + j) | ((unsigned)h << 10) | (bz_lo ? (1u << 20) : 0u);
        }
      }
      if (bz_lo) {
        cbb++;
        if (ug >= hg) {                        // certainly in mask
          s0 += 1.0f; s1 += gm;
          s2 += gm * (float)(c + j); s3 += gm * (float)h;
        }
      } else if (ub < hb) {                    // bz bracket candidate
        unsigned o = atomicAdd(&cnt[1], 1u);
        if (o < CAPB) Bb[o] = ub;
        if (ug >= lg) {                        // stats outcome uncertain
          unsigned o2 = atomicAdd(&cnt[2], 1u);
          if (o2 < CAPX) {
            Xg[o2] = ug; Xb[o2] = ub;
            Xa[o2] = (unsigned)(c + j) | ((unsigned)h << 10);
          }
        }
      }
    }
    a = b; an = bn;
  }

  // block-reduce partials (no global atomics anywhere)
  for (int off = 32; off; off >>= 1) {
    cbg += __shfl_down(cbg, off);
    cbb += __shfl_down(cbb, off);
    s0  += __shfl_down(s0, off);
    s1  += __shfl_down(s1, off);
    s2  += __shfl_down(s2, off);
    s3  += __shfl_down(s3, off);
  }
  __shared__ unsigned wcb[2][4];
  __shared__ float wss[4][4];
  if (lane == 0) {
    wcb[0][wave] = cbg; wcb[1][wave] = cbb;
    wss[0][wave] = s0; wss[1][wave] = s1; wss[2][wave] = s2; wss[3][wave] = s3;
  }
  __syncthreads();
  if (tx == 0) {
    ws->cbG[t][blk] = wcb[0][0] + wcb[0][1] + wcb[0][2] + wcb[0][3];
    ws->cbB[t][blk] = wcb[1][0] + wcb[1][1] + wcb[1][2] + wcb[1][3];
    ws->part[t][blk][0] = (double)wss[0][0] + wss[0][1] + wss[0][2] + wss[0][3];
    ws->part[t][blk][1] = (double)wss[1][0] + wss[1][1] + wss[1][2] + wss[1][3];
    ws->part[t][blk][2] = (double)wss[2][0] + wss[2][1] + wss[2][2] + wss[2][3];
    ws->part[t][blk][3] = (double)wss[3][0] + wss[3][1] + wss[3][2] + wss[3][3];
    ws->cntG[t][blk] = min(cnt[0], CAPG);
    ws->cntB[t][blk] = min(cnt[1], CAPB);
    ws->cntX[t][blk] = min(cnt[2], CAPX);
  }
}

// ---------------- pass 2: exact radix select over bracket candidates ----------
// Adaptive level count (bracket width hi-lo is known: typically ~2^16 -> 2 passes)
// + first pass caches candidate deltas in LDS so refine passes never touch global.
__global__ __launch_bounds__(SEL_THREADS) void select_kernel(WS* ws) {
  const int t = blockIdx.x, q = blockIdx.y, tx = threadIdx.x;
  __shared__ unsigned cache[CACHE_N];                 // 104 KB
  __shared__ unsigned hist[2048];                     // 8 KB
  __shared__ unsigned partial[SEL_THREADS], chunk_before[SEL_THREADS];
  __shared__ unsigned nseg[32], segbase[33];
  __shared__ unsigned sel[2];
  __shared__ unsigned shrank;
  const unsigned lo = ws->lo[q][t];
  const unsigned hi = ws->hi[q][t];
  if (tx < 32) nseg[tx] = (q == 0) ? ws->cntG[t][tx] : ws->cntB[t][tx];
  __syncthreads();
  if (tx == 0) {
    unsigned cb = 0, base = 0;
    for (int i = 0; i < 32; ++i) {
      segbase[i] = base; base += nseg[i];
      cb += (q == 0) ? ws->cbG[t][i] : ws->cbB[t][i];
    }
    segbase[32] = base;
    long long rk = (long long)((q == 0) ? RANK_G : RANK_B) - (long long)cb;
    if (rk < 0) rk = 0;
    if (base > 0 && rk >= (long long)base) rk = (long long)base - 1;
    shrank = (unsigned)rk;
  }
  __syncthreads();
  const unsigned total = segbase[32];
  if (total == 0) {                         // degenerate; bracket guaranteed non-empty normally
    if (tx == 0) ws->thr[q][t] = __uint_as_float(lo);
    return;
  }
  const unsigned range = hi - lo;           // all d = u - lo in [0, range)
  const int w = 32 - __clz(range | 1u);     // bits needed
  int sp = (w > 11) ? (w - 11) : 0;         // current bucket shift (2048 buckets)
  unsigned rank = shrank, base_val = 0;
  unsigned flt_span = 0xFFFFFFFFu;          // first level: no filter
  bool first = true;

  while (true) {
    for (int i = tx; i < 2048; i += SEL_THREADS) hist[i] = 0;
    __syncthreads();

    if (first) {
      // global sweep: histogram + fill LDS cache
      for (int blk = 0; blk < 32; ++blk) {
        const unsigned n = nseg[blk], sb = segbase[blk];
        const unsigned* __restrict__ ptr = (q == 0) ? ws->Gg[t][blk] : ws->Bb[t][blk];
        for (unsigned i = tx; i < n; i += SEL_THREADS) {
          unsigned d = ptr[i] - lo;
          unsigned slot = sb + i;
          if (slot < CACHE_N) cache[slot] = d;
          atomicAdd(&hist[d >> sp], 1u);
        }
      }
    } else {
      // refine from LDS cache (+ rare global overflow tail)
      const unsigned lim = (total < CACHE_N) ? total : CACHE_N;
      for (unsigned i = tx; i < lim; i += SEL_THREADS) {
        unsigned rel = cache[i] - base_val;  // wraps large if below base -> filtered
        if (rel < flt_span) atomicAdd(&hist[rel >> sp], 1u);
      }
      if (total > CACHE_N) {
        for (int blk = 0; blk < 32; ++blk) {
          const unsigned sb = segbase[blk], n = nseg[blk];
          if (sb + n <= CACHE_N) continue;
          const unsigned start = (sb < CACHE_N) ? (CACHE_N - sb) : 0;
          const unsigned* __restrict__ ptr = (q == 0) ? ws->Gg[t][blk] : ws->Bb[t][blk];
          for (unsigned i = start + tx; i < n; i += SEL_THREADS) {
            unsigned rel = (ptr[i] - lo) - base_val;
            if (rel < flt_span) atomicAdd(&hist[rel >> sp], 1u);
          }
        }
      }
    }
    __syncthreads();

    unsigned s = 0;
#pragma unroll
    for (int j = 0; j < 2048 / SEL_THREADS; ++j) s += hist[tx * (2048 / SEL_THREADS) + j];
    partial[tx] = s;
    __syncthreads();
    if (tx == 0) {
      unsigned cum = 0;
      for (int i = 0; i < SEL_THREADS; ++i) { chunk_before[i] = cum; cum += partial[i]; }
    }
    __syncthreads();
    unsigned cb2 = chunk_before[tx];
    if (rank >= cb2 && rank < cb2 + partial[tx]) {
      unsigned rem = rank - cb2, cum = 0;
#pragma unroll
      for (int j = 0; j < 2048 / SEL_THREADS; ++j) {
        unsigned hv = hist[tx * (2048 / SEL_THREADS) + j];
        if (rem < cum + hv) { sel[0] = tx * (2048 / SEL_THREADS) + j; sel[1] = rem - cum; break; }
        cum += hv;
      }
    }
    __syncthreads();
    rank = sel[1];
    base_val += sel[0] << sp;
    if (sp == 0) {
      if (tx == 0) ws->thr[q][t] = __uint_as_float(lo + base_val);
      break;
    }
    flt_span = 1u << sp;
    sp = (sp > 11) ? (sp - 11) : 0;
    first = false;
    __syncthreads();
  }
}

// ---------------- pass 3: resolve uncertain records against exact thresholds --
// 8 blocks per frame (4 segments each) for full-GPU occupancy.
__global__ __launch_bounds__(256) void resolve_kernel(WS* ws) {
  const int t = blockIdx.x, p = blockIdx.y, tx = threadIdx.x;
  const unsigned tg = __float_as_uint(ws->thr[0][t]);
  const unsigned tb = __float_as_uint(ws->thr[1][t]);
  float c = 0.f, sg = 0.f, sx = 0.f, sy = 0.f;
  for (int blk = p * 4; blk < p * 4 + 4; ++blk) {
    const unsigned nG = ws->cntG[t][blk];
    const unsigned* __restrict__ Gg = ws->Gg[t][blk];
    const unsigned* __restrict__ Ga = ws->Ga[t][blk];
    for (unsigned i = tx; i < nG; i += 256) {
      unsigned g = Gg[i], a = Ga[i];
      if (g > tg && (a & (1u << 20))) {
        float v = __uint_as_float(g);
        c += 1.f; sg += v;
        sx += v * (float)(a & 1023u);
        sy += v * (float)((a >> 10) & 1023u);
      }
    }
    const unsigned nX = ws->cntX[t][blk];
    const unsigned* __restrict__ Xg = ws->Xg[t][blk];
    const unsigned* __restrict__ Xb = ws->Xb[t][blk];
    const unsigned* __restrict__ Xa = ws->Xa[t][blk];
    for (unsigned i = tx; i < nX; i += 256) {
      unsigned g = Xg[i], bb = Xb[i], a = Xa[i];
      if (g > tg && bb < tb) {
        float v = __uint_as_float(g);
        c += 1.f; sg += v;
        sx += v * (float)(a & 1023u);
        sy += v * (float)((a >> 10) & 1023u);
      }
    }
  }
  double dc = c, dg = sg, dx = sx, dy = sy;
  if (tx < 4) {  // fold the certain-true partials for this block's 4 segments
    const double* pp = ws->part[t][p * 4 + tx];
    dc += pp[0]; dg += pp[1]; dx += pp[2]; dy += pp[3];
  }
  for (int off = 32; off; off >>= 1) {
    dc += __shfl_down(dc, off);
    dg += __shfl_down(dg, off);
    dx += __shfl_down(dx, off);
    dy += __shfl_down(dy, off);
  }
  __shared__ double pd[4][4];
  const int wave = tx >> 6, lane = tx & 63;
  if (lane == 0) { pd[0][wave] = dc; pd[1][wave] = dg; pd[2][wave] = dx; pd[3][wave] = dy; }
  __syncthreads();
  if (tx == 0) {
    ws->acc2[t][p][0] = pd[0][0] + pd[0][1] + pd[0][2] + pd[0][3];
    ws->acc2[t][p][1] = pd[1][0] + pd[1][1] + pd[1][2] + pd[1][3];
    ws->acc2[t][p][2] = pd[2][0] + pd[2][1] + pd[2][2] + pd[2][3];
    ws->acc2[t][p][3] = pd[3][0] + pd[3][1] + pd[3][2] + pd[3][3];
  }
}

// ---------------- finalize: per-frame stats -> conv -> 8 scalars ----------------
__global__ __launch_bounds__(64) void finalize_kernel(WS* ws,
                                                      const float* __restrict__ conv_w,
                                                      const float* __restrict__ conv_b,
                                                      float* __restrict__ out) {
  __shared__ float st[T_][4];
  __shared__ float s[T_][4];
  const int tx = threadIdx.x;
  if (tx < T_) {
    double cnt = 0.0, sgm = 0.0, swx = 0.0, swy = 0.0;
#pragma unroll
    for (int b = 0; b < RES_SPLIT; ++b) {
      cnt += ws->acc2[tx][b][0];
      sgm += ws->acc2[tx][b][1];
      swx += ws->acc2[tx][b][2];
      swy += ws->acc2[tx][b][3];
    }
    float pil  = fmaxf((float)cnt, 1e-6f);
    float wsum = fmaxf((float)sgm, 1e-6f);
    st[tx][0] = pil / (float)N_;
    st[tx][1] = (float)sgm / pil;
    st[tx][2] = (float)swx / wsum / (float)W_;
    st[tx][3] = (float)swy / wsum / (float)H_;
  }
  __syncthreads();
  if (tx < T_) {
#pragma unroll
    for (int c2 = 0; c2 < 4; ++c2) {
      float acc = conv_b[c2];
#pragma unroll
      for (int k = 0; k < 3; ++k) {
        int ti = tx + k - 1;
        if (ti >= 0 && ti < T_) acc += conv_w[c2 * 3 + k] * st[ti][c2];
      }
      s[tx][c2] = acc;
    }
  }
  __syncthreads();
  if (tx == 0) {
    float lm = 0.f, im = 0.f;
    for (int i = 0; i < T_; ++i) { lm += s[i][0]; im += s[i][1]; }
    lm /= (float)T_; im /= (float)T_;
    float lt = 0.f, it = 0.f;
    for (int i = 0; i < T_; ++i) {
      float tn = (float)i / (float)(T_ - 1) - 0.5f;
      lt += (s[i][0] - lm) * tn;
      it += (s[i][1] - im) * tn;
    }
    lt *= 6.0f / (float)T_;
    it *= 6.0f / (float)T_;
    float speeds[T_ - 1];
    float spsum = 0.f, sdx = 0.f, sdy = 0.f;
    for (int i = 0; i < T_ - 1; ++i) {
      float dx = s[i + 1][2] - s[i][2];
      float dy = s[i + 1][3] - s[i][3];
      float sp = sqrtf(dx * dx + dy * dy);
      speeds[i] = sp; spsum += sp; sdx += dx; sdy += dy;
    }
    float ms  = spsum / (float)(T_ - 1);
    float dir = atan2f(sdy, sdx) / 3.14159265358979323846f;
    float gr  = (s[T_ - 1][0] - s[0][0]) / (float)(T_ - 1);
    float var = 0.f;
    for (int i = 0; i < T_ - 1; ++i) { float d = speeds[i] - ms; var += d * d; }
    float inst = sqrtf(var / (float)(T_ - 2));
    out[0] = lm; out[1] = lt; out[2] = im; out[3] = it;
    out[4] = ms; out[5] = dir; out[6] = gr; out[7] = inst;
  }
}

// ---------------- launch ----------------
extern "C" void kernel_launch(void* const* d_in, const int* in_sizes, int n_in,
                              void* d_out, int out_size, void* d_ws, size_t ws_size,
                              hipStream_t stream) {
  const float* frames = (const float*)d_in[0];
  const float* conv_w = (const float*)d_in[2];
  const float* conv_b = (const float*)d_in[3];
  float* out = (float*)d_out;
  WS* ws = (WS*)d_ws;

  // no memset needed: every WS field consumed is written unconditionally first

  sample_kernel<<<T_, 256, 0, stream>>>(frames, ws);
  main_kernel<<<dim3(BLOCKS_PER_FRAME, T_), 256, 0, stream>>>(frames, ws);
  select_kernel<<<dim3(T_, 2), SEL_THREADS, 0, stream>>>(ws);
  resolve_kernel<<<dim3(T_, RES_SPLIT), 256, 0, stream>>>(ws);
  finalize_kernel<<<1, 64, 0, stream>>>(ws, conv_w, conv_b, out);
}

// Round 3
// 502.750 us; speedup vs baseline: 1.2604x; 1.0210x over previous
//
#include <hip/hip_runtime.h>
#include <math.h>
#include <stddef.h>

// ---------------- problem constants ----------------
constexpr int T_ = 64;
constexpr int H_ = 1024;
constexpr int W_ = 1024;
constexpr int N_ = H_ * W_;
// int((1.0-0.15)*(N-1)) and int(0.3*(N-1)) with python double semantics
constexpr unsigned RANK_G = 891288;   // 85th pct index of gm (ascending, 0-based)
constexpr unsigned RANK_B = 314572;   // 30th pct index of |f|

constexpr int ROWS_PER_BLOCK = 32;
constexpr int BLOCKS_PER_FRAME = H_ / ROWS_PER_BLOCK; // 32

// sampling: 16 rows/frame = 16384 samples; N/NS = 64
constexpr int SROWS = 16;
constexpr int NS = SROWS * W_;              // 16384
constexpr int SHB = 8192;                   // stage-1 buckets (u>>18)
constexpr int MARGIN = 192;                 // sample-rank margin (~4.4 sigma in pop rank)
constexpr int RS_G = (int)(RANK_G / 64);    // 13926
constexpr int RS_B = (int)(RANK_B / 64);    // 4915

// per-block segment capacities (expected ~770 / ~770 / ~125)
constexpr unsigned CAPG = 1536;
constexpr unsigned CAPB = 1536;
constexpr unsigned CAPX = 448;

// select kernel LDS cache of candidate deltas (104 KB); expected total ~24.6K
constexpr unsigned CACHE_N = 26624;
constexpr int SEL_THREADS = 512;

// resolve parallelism: 8 blocks per frame, 4 segments each
constexpr int RES_SPLIT = 8;

// native vector type for nontemporal loads (builtin rejects HIP_vector_type)
typedef float f4_t __attribute__((ext_vector_type(4)));

// ---------------- workspace layout (~49 MB) ----------------
struct WS {
  unsigned lo[2][T_], hi[2][T_];       // refined value brackets (bit patterns)
  unsigned cntG[T_][32], cntB[T_][32], cntX[T_][32];
  unsigned cbG[T_][32], cbB[T_][32];   // per-block #{u < lo}
  float    thr[2][T_];
  double   part[T_][32][4];            // per-block certain-true partial stats
  double   acc2[T_][RES_SPLIT][4];     // resolve partials: cnt, sum_gm, sum_gm*x, sum_gm*y
  unsigned Gg[T_][32][CAPG];           // gm bracket candidates: gm bits
  unsigned Ga[T_][32][CAPG];           //   aux: x|y<<10|certain_bz_flag<<20
  unsigned Bb[T_][32][CAPB];           // bz bracket candidates: bz bits
  unsigned Xg[T_][32][CAPX];           // uncertain-stats records (bz in bracket, gm >= lo_g)
  unsigned Xb[T_][32][CAPX];
  unsigned Xa[T_][32][CAPX];           //   aux: x|y<<10
};

// Shared gm computation so every pass rounds identically.
__device__ __forceinline__ float gm_at(float cur, float right, float down,
                                       int col, int row) {
  float gx = (col < W_ - 1) ? (right - cur) : 0.0f;
  float gy = (row < H_ - 1) ? (down - cur) : 0.0f;
  return sqrtf(gx * gx + gy * gy);
}

// Block-wide exclusive prefix sum via wave shuffles (replaces serial tx==0 scans).
// Must be called in uniform control flow. wsum must hold >= NT/64 entries.
template <int NT>
__device__ __forceinline__ unsigned excl_scan_block(unsigned v, int tx,
                                                    volatile unsigned* wsum) {
  const int lane = tx & 63, wv = tx >> 6;
  unsigned s = v;
#pragma unroll
  for (int o = 1; o < 64; o <<= 1) {
    unsigned u = __shfl_up(s, o);
    if (lane >= o) s += u;
  }
  if (lane == 63) wsum[wv] = s;
  __syncthreads();
  unsigned base = 0;
#pragma unroll
  for (int w = 0; w < NT / 64; ++w)
    if (w < wv) base += wsum[w];
  __syncthreads();            // wsum reusable by the next call
  return base + s - v;        // exclusive prefix
}

// ---------------- pass 0: sampled bracket estimation (2-stage refine) ----------
__global__ __launch_bounds__(256) void sample_kernel(const float* __restrict__ frames,
                                                     WS* ws) {
  const int t = blockIdx.x;
  __shared__ unsigned hist[2][SHB];        // 64 KB
  __shared__ unsigned sub[4][1024];        // 16 KB, (q*2+e)
  __shared__ unsigned wscan[4];
  __shared__ unsigned selB[4], selCB[4];
  const int tx = threadIdx.x, c = tx * 4, lane = tx & 63;
  for (int i = tx; i < 2 * SHB; i += 256) (&hist[0][0])[i] = 0;
  for (int i = tx; i < 4 * 1024; i += 256) (&sub[0][0])[i] = 0;
  __syncthreads();
  const float* f = frames + (size_t)t * N_;

  // stage-1 histogram over 16 sampled rows (unrolled for load pipelining)
#pragma unroll 4
  for (int r = 0; r < SROWS; ++r) {
    const int h = r * 64 + 32;                 // 32..992, h+1 always valid
    const float* row = f + (size_t)h * W_;
    f4_t a = *(const f4_t*)(row + c);
    f4_t b = *(const f4_t*)(row + W_ + c);
    float an = __shfl_down(a.x, 1);            // lane tx+1's a.x == row[c+4]
    if (lane == 63) an = (c + 4 < W_) ? row[c + 4] : 0.0f;
    float xs[5] = {a.x, a.y, a.z, a.w, an};
    float ys[4] = {b.x, b.y, b.z, b.w};
#pragma unroll
    for (int j = 0; j < 4; ++j) {
      float gm = gm_at(xs[j], xs[j + 1], ys[j], c + j, h);
      float bz = fabsf(xs[j]);
      atomicAdd(&hist[0][__float_as_uint(gm) >> 18], 1u);
      atomicAdd(&hist[1][__float_as_uint(bz) >> 18], 1u);
    }
  }
  __syncthreads();

  // stage-1 select: bucket + count-below-bucket for each (q, endpoint)
  for (int q = 0; q < 2; ++q) {
    unsigned s = 0;
#pragma unroll
    for (int j = 0; j < SHB / 256; ++j) s += hist[q][tx * (SHB / 256) + j];
    unsigned cb = excl_scan_block<256>(s, tx, wscan);
#pragma unroll
    for (int e = 0; e < 2; ++e) {
      int k = (q == 0 ? RS_G : RS_B) + (e == 0 ? -MARGIN : MARGIN);
      if ((unsigned)k >= cb && (unsigned)k < cb + s) {
        unsigned rem = (unsigned)k - cb, cum = 0;
        for (int j = 0; j < SHB / 256; ++j) {
          unsigned hv = hist[q][tx * (SHB / 256) + j];
          if (rem < cum + hv) {
            selB[q * 2 + e]  = tx * (SHB / 256) + j;
            selCB[q * 2 + e] = cb + cum;
            break;
          }
          cum += hv;
        }
      }
    }
    __syncthreads();
  }

  // stage-2 histogram: re-read samples (L2-warm), refine within selected buckets
#pragma unroll 4
  for (int r = 0; r < SROWS; ++r) {
    const int h = r * 64 + 32;
    const float* row = f + (size_t)h * W_;
    f4_t a = *(const f4_t*)(row + c);
    f4_t b = *(const f4_t*)(row + W_ + c);
    float an = __shfl_down(a.x, 1);
    if (lane == 63) an = (c + 4 < W_) ? row[c + 4] : 0.0f;
    float xs[5] = {a.x, a.y, a.z, a.w, an};
    float ys[4] = {b.x, b.y, b.z, b.w};
#pragma unroll
    for (int j = 0; j < 4; ++j) {
      float gm = gm_at(xs[j], xs[j + 1], ys[j], c + j, h);
      float bz = fabsf(xs[j]);
      unsigned ug = __float_as_uint(gm), ub = __float_as_uint(bz);
#pragma unroll
      for (int e = 0; e < 2; ++e) {
        if ((ug >> 18) == selB[e])     atomicAdd(&sub[e][(ug >> 8) & 1023u], 1u);
        if ((ub >> 18) == selB[2 + e]) atomicAdd(&sub[2 + e][(ub >> 8) & 1023u], 1u);
      }
    }
  }
  __syncthreads();

  // stage-2 select per (q,e) -> refined bound at 2^8 bit granularity
  for (int qe = 0; qe < 4; ++qe) {
    unsigned s = 0;
#pragma unroll
    for (int j = 0; j < 4; ++j) s += sub[qe][tx * 4 + j];
    unsigned cb = excl_scan_block<256>(s, tx, wscan);
    int q = qe >> 1, e = qe & 1;
    int k0 = (q == 0 ? RS_G : RS_B) + (e == 0 ? -MARGIN : MARGIN);
    unsigned k = (unsigned)k0 - selCB[qe];      // rank within bucket
    if (k >= cb && k < cb + s) {
      unsigned rem = k - cb, cum = 0;
      for (int j = 0; j < 4; ++j) {
        unsigned hv = sub[qe][tx * 4 + j];
        if (rem < cum + hv) {
          unsigned sb = tx * 4 + j;
          unsigned bound = (selB[qe] << 18) | (sb << 8);
          if (e == 0) ws->lo[q][t] = bound;
          else        ws->hi[q][t] = bound + 256u;
          break;
        }
        cum += hv;
      }
    }
    __syncthreads();
  }
}

// ---------------- pass 1: the ONLY full streaming pass ----------------
__global__ __launch_bounds__(256) void main_kernel(const float* __restrict__ frames,
                                                   WS* ws) {
  const int t = blockIdx.y, blk = blockIdx.x, r0 = blk * ROWS_PER_BLOCK;
  const unsigned lg = ws->lo[0][t], hg = ws->hi[0][t];
  const unsigned lb = ws->lo[1][t], hb = ws->hi[1][t];
  __shared__ unsigned cnt[3];
  const int tx = threadIdx.x, c = tx * 4, lane = tx & 63, wave = tx >> 6;
  if (tx < 3) cnt[tx] = 0;
  __syncthreads();
  unsigned* __restrict__ Gg = ws->Gg[t][blk];
  unsigned* __restrict__ Ga = ws->Ga[t][blk];
  unsigned* __restrict__ Bb = ws->Bb[t][blk];
  unsigned* __restrict__ Xg = ws->Xg[t][blk];
  unsigned* __restrict__ Xb = ws->Xb[t][blk];
  unsigned* __restrict__ Xa = ws->Xa[t][blk];
  const float* f = frames + (size_t)t * N_;

  unsigned cbg = 0, cbb = 0;
  float s0 = 0.f, s1 = 0.f, s2 = 0.f, s3 = 0.f;

  // register-carry the row: row h+1 loaded once as `b`, reused as `a` next iter.
  // frames are streamed once -> nontemporal so candidate arrays stay in L2.
  const float* row0 = f + (size_t)r0 * W_;
  f4_t a = __builtin_nontemporal_load((const f4_t*)(row0 + c));
  float an = __shfl_down(a.x, 1);              // lane tx+1's a.x == row0[c+4]
  if (lane == 63) an = (c + 4 < W_) ? row0[c + 4] : 0.0f;

#pragma unroll 2
  for (int r = 0; r < ROWS_PER_BLOCK; ++r) {
    const int h = r0 + r;
    f4_t b; float bn;
    if (h + 1 < H_) {
      const float* rowN = f + (size_t)(h + 1) * W_;
      b  = __builtin_nontemporal_load((const f4_t*)(rowN + c));
      bn = __shfl_down(b.x, 1);
      if (lane == 63) bn = (c + 4 < W_) ? rowN[c + 4] : 0.0f;
    } else {
      b = a; bn = an;                         // forces gy = 0
    }
    float xs[5] = {a.x, a.y, a.z, a.w, an};
    float ys[4] = {b.x, b.y, b.z, b.w};
#pragma unroll
    for (int j = 0; j < 4; ++j) {
      float gm = gm_at(xs[j], xs[j + 1], ys[j], c + j, h);
      float bz = fabsf(xs[j]);
      unsigned ug = __float_as_uint(gm);
      unsigned ub = __float_as_uint(bz);
      bool bz_lo = (ub < lb);
      if (ug < lg) {
        cbg++;
      } else if (ug < hg) {                    // gm bracket candidate
        unsigned o = atomicAdd(&cnt[0], 1u);
        if (o < CAPG) {
          Gg[o] = ug;
          Ga[o] = (unsigned)(c + j) | ((unsigned)h << 10) | (bz_lo ? (1u << 20) : 0u);
        }
      }
      if (bz_lo) {
        cbb++;
        if (ug >= hg) {                        // certainly in mask
          s0 += 1.0f; s1 += gm;
          s2 += gm * (float)(c + j); s3 += gm * (float)h;
        }
      } else if (ub < hb) {                    // bz bracket candidate
        unsigned o = atomicAdd(&cnt[1], 1u);
        if (o < CAPB) Bb[o] = ub;
        if (ug >= lg) {                        // stats outcome uncertain
          unsigned o2 = atomicAdd(&cnt[2], 1u);
          if (o2 < CAPX) {
            Xg[o2] = ug; Xb[o2] = ub;
            Xa[o2] = (unsigned)(c + j) | ((unsigned)h << 10);
          }
        }
      }
    }
    a = b; an = bn;
  }

  // block-reduce partials (no global atomics anywhere)
  for (int off = 32; off; off >>= 1) {
    cbg += __shfl_down(cbg, off);
    cbb += __shfl_down(cbb, off);
    s0  += __shfl_down(s0, off);
    s1  += __shfl_down(s1, off);
    s2  += __shfl_down(s2, off);
    s3  += __shfl_down(s3, off);
  }
  __shared__ unsigned wcb[2][4];
  __shared__ float wss[4][4];
  if (lane == 0) {
    wcb[0][wave] = cbg; wcb[1][wave] = cbb;
    wss[0][wave] = s0; wss[1][wave] = s1; wss[2][wave] = s2; wss[3][wave] = s3;
  }
  __syncthreads();
  if (tx == 0) {
    ws->cbG[t][blk] = wcb[0][0] + wcb[0][1] + wcb[0][2] + wcb[0][3];
    ws->cbB[t][blk] = wcb[1][0] + wcb[1][1] + wcb[1][2] + wcb[1][3];
    ws->part[t][blk][0] = (double)wss[0][0] + wss[0][1] + wss[0][2] + wss[0][3];
    ws->part[t][blk][1] = (double)wss[1][0] + wss[1][1] + wss[1][2] + wss[1][3];
    ws->part[t][blk][2] = (double)wss[2][0] + wss[2][1] + wss[2][2] + wss[2][3];
    ws->part[t][blk][3] = (double)wss[3][0] + wss[3][1] + wss[3][2] + wss[3][3];
    ws->cntG[t][blk] = min(cnt[0], CAPG);
    ws->cntB[t][blk] = min(cnt[1], CAPB);
    ws->cntX[t][blk] = min(cnt[2], CAPX);
  }
}

// ---------------- pass 2: exact radix select over bracket candidates ----------
// Adaptive level count (bracket width hi-lo is known: typically ~2^18 -> 2 passes)
// + first pass caches candidate deltas in LDS so refine passes never touch global.
__global__ __launch_bounds__(SEL_THREADS) void select_kernel(WS* ws) {
  const int t = blockIdx.x, q = blockIdx.y, tx = threadIdx.x;
  __shared__ unsigned cache[CACHE_N];                 // 104 KB
  __shared__ unsigned hist[2048];                     // 8 KB
  __shared__ unsigned wscan[SEL_THREADS / 64];
  __shared__ unsigned nseg[32], segbase[33];
  __shared__ unsigned sel[2];
  __shared__ unsigned shrank;
  const unsigned lo = ws->lo[q][t];
  const unsigned hi = ws->hi[q][t];
  if (tx < 32) nseg[tx] = (q == 0) ? ws->cntG[t][tx] : ws->cntB[t][tx];
  __syncthreads();
  if (tx == 0) {
    unsigned cb = 0, base = 0;
    for (int i = 0; i < 32; ++i) {
      segbase[i] = base; base += nseg[i];
      cb += (q == 0) ? ws->cbG[t][i] : ws->cbB[t][i];
    }
    segbase[32] = base;
    long long rk = (long long)((q == 0) ? RANK_G : RANK_B) - (long long)cb;
    if (rk < 0) rk = 0;
    if (base > 0 && rk >= (long long)base) rk = (long long)base - 1;
    shrank = (unsigned)rk;
  }
  __syncthreads();
  const unsigned total = segbase[32];
  if (total == 0) {                         // degenerate; bracket guaranteed non-empty normally
    if (tx == 0) ws->thr[q][t] = __uint_as_float(lo);
    return;
  }
  const unsigned range = hi - lo;           // all d = u - lo in [0, range)
  const int w = 32 - __clz(range | 1u);     // bits needed
  int sp = (w > 11) ? (w - 11) : 0;         // current bucket shift (2048 buckets)
  unsigned rank = shrank, base_val = 0;
  unsigned flt_span = 0xFFFFFFFFu;          // first level: no filter
  bool first = true;

  while (true) {
    for (int i = tx; i < 2048; i += SEL_THREADS) hist[i] = 0;
    __syncthreads();

    if (first) {
      // global sweep: histogram + fill LDS cache
      for (int blk = 0; blk < 32; ++blk) {
        const unsigned n = nseg[blk], sb = segbase[blk];
        const unsigned* __restrict__ ptr = (q == 0) ? ws->Gg[t][blk] : ws->Bb[t][blk];
        for (unsigned i = tx; i < n; i += SEL_THREADS) {
          unsigned d = ptr[i] - lo;
          unsigned slot = sb + i;
          if (slot < CACHE_N) cache[slot] = d;
          atomicAdd(&hist[d >> sp], 1u);
        }
      }
    } else {
      // refine from LDS cache (+ rare global overflow tail)
      const unsigned lim = (total < CACHE_N) ? total : CACHE_N;
      for (unsigned i = tx; i < lim; i += SEL_THREADS) {
        unsigned rel = cache[i] - base_val;  // wraps large if below base -> filtered
        if (rel < flt_span) atomicAdd(&hist[rel >> sp], 1u);
      }
      if (total > CACHE_N) {
        for (int blk = 0; blk < 32; ++blk) {
          const unsigned sb = segbase[blk], n = nseg[blk];
          if (sb + n <= CACHE_N) continue;
          const unsigned start = (sb < CACHE_N) ? (CACHE_N - sb) : 0;
          const unsigned* __restrict__ ptr = (q == 0) ? ws->Gg[t][blk] : ws->Bb[t][blk];
          for (unsigned i = start + tx; i < n; i += SEL_THREADS) {
            unsigned rel = (ptr[i] - lo) - base_val;
            if (rel < flt_span) atomicAdd(&hist[rel >> sp], 1u);
          }
        }
      }
    }
    __syncthreads();

    unsigned s = 0;
#pragma unroll
    for (int j = 0; j < 2048 / SEL_THREADS; ++j) s += hist[tx * (2048 / SEL_THREADS) + j];
    unsigned cb2 = excl_scan_block<SEL_THREADS>(s, tx, wscan);
    if (rank >= cb2 && rank < cb2 + s) {
      unsigned rem = rank - cb2, cum = 0;
#pragma unroll
      for (int j = 0; j < 2048 / SEL_THREADS; ++j) {
        unsigned hv = hist[tx * (2048 / SEL_THREADS) + j];
        if (rem < cum + hv) { sel[0] = tx * (2048 / SEL_THREADS) + j; sel[1] = rem - cum; break; }
        cum += hv;
      }
    }
    __syncthreads();
    rank = sel[1];
    base_val += sel[0] << sp;
    if (sp == 0) {
      if (tx == 0) ws->thr[q][t] = __uint_as_float(lo + base_val);
      break;
    }
    flt_span = 1u << sp;
    sp = (sp > 11) ? (sp - 11) : 0;
    first = false;
    __syncthreads();
  }
}

// ---------------- pass 3: resolve uncertain records against exact thresholds --
// 8 blocks per frame (4 segments each) for full-GPU occupancy.
__global__ __launch_bounds__(256) void resolve_kernel(WS* ws) {
  const int t = blockIdx.x, p = blockIdx.y, tx = threadIdx.x;
  const unsigned tg = __float_as_uint(ws->thr[0][t]);
  const unsigned tb = __float_as_uint(ws->thr[1][t]);
  float c = 0.f, sg = 0.f, sx = 0.f, sy = 0.f;
  for (int blk = p * 4; blk < p * 4 + 4; ++blk) {
    const unsigned nG = ws->cntG[t][blk];
    const unsigned* __restrict__ Gg = ws->Gg[t][blk];
    const unsigned* __restrict__ Ga = ws->Ga[t][blk];
    for (unsigned i = tx; i < nG; i += 256) {
      unsigned g = Gg[i], a = Ga[i];
      if (g > tg && (a & (1u << 20))) {
        float v = __uint_as_float(g);
        c += 1.f; sg += v;
        sx += v * (float)(a & 1023u);
        sy += v * (float)((a >> 10) & 1023u);
      }
    }
    const unsigned nX = ws->cntX[t][blk];
    const unsigned* __restrict__ Xg = ws->Xg[t][blk];
    const unsigned* __restrict__ Xb = ws->Xb[t][blk];
    const unsigned* __restrict__ Xa = ws->Xa[t][blk];
    for (unsigned i = tx; i < nX; i += 256) {
      unsigned g = Xg[i], bb = Xb[i], a = Xa[i];
      if (g > tg && bb < tb) {
        float v = __uint_as_float(g);
        c += 1.f; sg += v;
        sx += v * (float)(a & 1023u);
        sy += v * (float)((a >> 10) & 1023u);
      }
    }
  }
  double dc = c, dg = sg, dx = sx, dy = sy;
  if (tx < 4) {  // fold the certain-true partials for this block's 4 segments
    const double* pp = ws->part[t][p * 4 + tx];
    dc += pp[0]; dg += pp[1]; dx += pp[2]; dy += pp[3];
  }
  for (int off = 32; off; off >>= 1) {
    dc += __shfl_down(dc, off);
    dg += __shfl_down(dg, off);
    dx += __shfl_down(dx, off);
    dy += __shfl_down(dy, off);
  }
  __shared__ double pd[4][4];
  const int wave = tx >> 6, lane = tx & 63;
  if (lane == 0) { pd[0][wave] = dc; pd[1][wave] = dg; pd[2][wave] = dx; pd[3][wave] = dy; }
  __syncthreads();
  if (tx == 0) {
    ws->acc2[t][p][0] = pd[0][0] + pd[0][1] + pd[0][2] + pd[0][3];
    ws->acc2[t][p][1] = pd[1][0] + pd[1][1] + pd[1][2] + pd[1][3];
    ws->acc2[t][p][2] = pd[2][0] + pd[2][1] + pd[2][2] + pd[2][3];
    ws->acc2[t][p][3] = pd[3][0] + pd[3][1] + pd[3][2] + pd[3][3];
  }
}

// ---------------- finalize: per-frame stats -> conv -> 8 scalars ----------------
__global__ __launch_bounds__(64) void finalize_kernel(WS* ws,
                                                      const float* __restrict__ conv_w,
                                                      const float* __restrict__ conv_b,
                                                      float* __restrict__ out) {
  __shared__ float st[T_][4];
  __shared__ float s[T_][4];
  const int tx = threadIdx.x;
  if (tx < T_) {
    double cnt = 0.0, sgm = 0.0, swx = 0.0, swy = 0.0;
#pragma unroll
    for (int b = 0; b < RES_SPLIT; ++b) {
      cnt += ws->acc2[tx][b][0];
      sgm += ws->acc2[tx][b][1];
      swx += ws->acc2[tx][b][2];
      swy += ws->acc2[tx][b][3];
    }
    float pil  = fmaxf((float)cnt, 1e-6f);
    float wsum = fmaxf((float)sgm, 1e-6f);
    st[tx][0] = pil / (float)N_;
    st[tx][1] = (float)sgm / pil;
    st[tx][2] = (float)swx / wsum / (float)W_;
    st[tx][3] = (float)swy / wsum / (float)H_;
  }
  __syncthreads();
  if (tx < T_) {
#pragma unroll
    for (int c2 = 0; c2 < 4; ++c2) {
      float acc = conv_b[c2];
#pragma unroll
      for (int k = 0; k < 3; ++k) {
        int ti = tx + k - 1;
        if (ti >= 0 && ti < T_) acc += conv_w[c2 * 3 + k] * st[ti][c2];
      }
      s[tx][c2] = acc;
    }
  }
  __syncthreads();
  if (tx == 0) {
    float lm = 0.f, im = 0.f;
    for (int i = 0; i < T_; ++i) { lm += s[i][0]; im += s[i][1]; }
    lm /= (float)T_; im /= (float)T_;
    float lt = 0.f, it = 0.f;
    for (int i = 0; i < T_; ++i) {
      float tn = (float)i / (float)(T_ - 1) - 0.5f;
      lt += (s[i][0] - lm) * tn;
      it += (s[i][1] - im) * tn;
    }
    lt *= 6.0f / (float)T_;
    it *= 6.0f / (float)T_;
    float speeds[T_ - 1];
    float spsum = 0.f, sdx = 0.f, sdy = 0.f;
    for (int i = 0; i < T_ - 1; ++i) {
      float dx = s[i + 1][2] - s[i][2];
      float dy = s[i + 1][3] - s[i][3];
      float sp = sqrtf(dx * dx + dy * dy);
      speeds[i] = sp; spsum += sp; sdx += dx; sdy += dy;
    }
    float ms  = spsum / (float)(T_ - 1);
    float dir = atan2f(sdy, sdx) / 3.14159265358979323846f;
    float gr  = (s[T_ - 1][0] - s[0][0]) / (float)(T_ - 1);
    float var = 0.f;
    for (int i = 0; i < T_ - 1; ++i) { float d = speeds[i] - ms; var += d * d; }
    float inst = sqrtf(var / (float)(T_ - 2));
    out[0] = lm; out[1] = lt; out[2] = im; out[3] = it;
    out[4] = ms; out[5] = dir; out[6] = gr; out[7] = inst;
  }
}

// ---------------- launch ----------------
extern "C" void kernel_launch(void* const* d_in, const int* in_sizes, int n_in,
                              void* d_out, int out_size, void* d_ws, size_t ws_size,
                              hipStream_t stream) {
  const float* frames = (const float*)d_in[0];
  const float* conv_w = (const float*)d_in[2];
  const float* conv_b = (const float*)d_in[3];
  float* out = (float*)d_out;
  WS* ws = (WS*)d_ws;

  // no memset needed: every WS field consumed is written unconditionally first

  sample_kernel<<<T_, 256, 0, stream>>>(frames, ws);
  main_kernel<<<dim3(BLOCKS_PER_FRAME, T_), 256, 0, stream>>>(frames, ws);
  select_kernel<<<dim3(T_, 2), SEL_THREADS, 0, stream>>>(ws);
  resolve_kernel<<<dim3(T_, RES_SPLIT), 256, 0, stream>>>(ws);
  finalize_kernel<<<1, 64, 0, stream>>>(ws, conv_w, conv_b, out);
}